// Round 1
// baseline (20.303 us; speedup 1.0000x reference)
//
#include <hip/hip_runtime.h>

#define RPB 8        // rows per block; 1408 = 176 * 8
#define D   256      // LN / fc input dim
#define F   128      // fc output dim
#define C   10       // classes
#define LN_EPS 1e-5f

__global__ __launch_bounds__(256, 1) void logreg_fused(
    const float* __restrict__ seq,   const float* __restrict__ ln_g,
    const float* __restrict__ ln_b,  const float* __restrict__ fc_w,
    const float* __restrict__ fc_b,  const float* __restrict__ mlp_w,
    const float* __restrict__ mlp_b, float* __restrict__ out)
{
    __shared__ float4 sxn4[RPB][D / 4];   // normalized rows (float4 layout)
    __shared__ float  sh[RPB][F + 1];     // sigmoid outputs; +1 pad breaks 128-stride banks

    const int t    = threadIdx.x;
    const int wave = t >> 6;
    const int lane = t & 63;
    const int rowbase = blockIdx.x * RPB;

    // ---------- Phase 1: LayerNorm. Wave w handles rows w and w+4. ----------
    {
        const float4 gv = ((const float4*)ln_g)[lane];
        const float4 bv = ((const float4*)ln_b)[lane];
        #pragma unroll
        for (int rr = 0; rr < 2; ++rr) {
            const int r = wave + rr * 4;
            float4 v = ((const float4*)(seq + (size_t)(rowbase + r) * D))[lane];
            float s  = v.x + v.y + v.z + v.w;
            float ss = v.x * v.x + v.y * v.y + v.z * v.z + v.w * v.w;
            #pragma unroll
            for (int off = 32; off > 0; off >>= 1) {
                s  += __shfl_xor(s,  off);
                ss += __shfl_xor(ss, off);
            }
            const float mean = s * (1.0f / D);
            const float var  = ss * (1.0f / D) - mean * mean;
            const float inv  = rsqrtf(var + LN_EPS);
            float4 o4;
            o4.x = (v.x - mean) * inv * gv.x + bv.x;
            o4.y = (v.y - mean) * inv * gv.y + bv.y;
            o4.z = (v.z - mean) * inv * gv.z + bv.z;
            o4.w = (v.w - mean) * inv * gv.w + bv.w;
            sxn4[r][lane] = o4;
        }
    }
    __syncthreads();

    // ---------- Phase 2: fc 256->128 GEMV + sigmoid. ----------
    // Thread t: output feature o = t & 127, rows [half*4, half*4+4).
    {
        const int o    = t & 127;
        const int half = t >> 7;      // wave-uniform (waves 0,1 -> 0; waves 2,3 -> 1)
        const int r0   = half * 4;
        const float bias = fc_b[o];
        float acc[4] = {bias, bias, bias, bias};
        const float4* __restrict__ wrow = (const float4*)(fc_w + (size_t)o * D);
        #pragma unroll
        for (int kc = 0; kc < D / 4; kc += 8) {
            float4 w[8];
            #pragma unroll
            for (int j = 0; j < 8; ++j) w[j] = wrow[kc + j];
            #pragma unroll
            for (int r = 0; r < 4; ++r) {
                #pragma unroll
                for (int j = 0; j < 8; ++j) {
                    const float4 xv = sxn4[r0 + r][kc + j];   // uniform addr -> LDS broadcast
                    acc[r] += w[j].x * xv.x + w[j].y * xv.y
                            + w[j].z * xv.z + w[j].w * xv.w;
                }
            }
        }
        #pragma unroll
        for (int r = 0; r < 4; ++r)
            sh[r0 + r][o] = 1.0f / (1.0f + __expf(-acc[r]));
    }
    __syncthreads();

    // ---------- Phase 3: mlp 128->10. Two threads per (row, class). ----------
    if (t < RPB * C * 2) {
        const int oid  = t >> 1;
        const int half = t & 1;
        const int r    = oid / C;
        const int c    = oid % C;
        const float* __restrict__ wrow = mlp_w + (size_t)c * F;
        float s = 0.0f;
        #pragma unroll
        for (int f = half * 64; f < half * 64 + 64; ++f)
            s += sh[r][f] * wrow[f];
        s += __shfl_xor(s, 1);       // combine the two halves
        if (half == 0)
            out[(size_t)(rowbase + r) * C + c] = s + mlp_b[c];
    }
}

extern "C" void kernel_launch(void* const* d_in, const int* in_sizes, int n_in,
                              void* d_out, int out_size, void* d_ws, size_t ws_size,
                              hipStream_t stream)
{
    const float* seq   = (const float*)d_in[0];
    const float* ln_g  = (const float*)d_in[1];
    const float* ln_b  = (const float*)d_in[2];
    const float* fc_w  = (const float*)d_in[3];
    const float* fc_b  = (const float*)d_in[4];
    const float* mlp_w = (const float*)d_in[5];
    const float* mlp_b = (const float*)d_in[6];
    float* out = (float*)d_out;

    const int n_rows = 1408;                 // 32*4*11
    const int grid   = n_rows / RPB;         // 176 blocks
    logreg_fused<<<grid, 256, 0, stream>>>(seq, ln_g, ln_b, fc_w, fc_b,
                                           mlp_w, mlp_b, out);
}